// Round 1
// baseline (245.916 us; speedup 1.0000x reference)
//
#include <hip/hip_runtime.h>

// db2 coefficients (standard Daubechies-2, matches reference construction)
constexpr float h0 = 0.48296291314469025f;  // (1+√3)/(4√2)
constexpr float h1 = 0.83651630373746900f;  // (3+√3)/(4√2)
constexpr float h2 = 0.22414386804185735f;  // (3-√3)/(4√2)
constexpr float h3 = -0.12940952255092145f; // (1-√3)/(4√2)

// lpf = [h3,h2,h1,h0]; hpf = [-h0,h1,-h2,h3]
// Output row r = 2m+er taps orig rows m, min(m+1,511).
//   lpf vertical: er=0 -> (h2, h0); er=1 -> (h3, h1)
//   hpf vertical: er=0 -> (h1, h3); er=1 -> (-h0, -h2)
// Channels: c0,c1 = (lpf,lpf) [LH replicates source bug -> pre-summed A=x+y];
// c2 = (lpf_h, hpf_w); c3 = (hpf_h, hpf_w); c2,c3 share horizontal hpf.
//
// V2: vertical register-blocking. Each thread handles R=4 consecutive input
// rows (reads R+1=5 rows x 3 float4, writes 2R=8 output float4), so interior
// rows are read ONCE instead of twice; only the strip-boundary row (1 in 4)
// is re-read, and the XCD-aware block swizzle puts adjacent strips on the
// same XCD so that re-read is an L2 hit instead of an HBM fetch.

constexpr int R = 4;  // input rows per thread

__global__ __launch_bounds__(256) void idwt_kernel(const float4* __restrict__ x,
                                                   float4* __restrict__ out) {
    // XCD-aware bijective swizzle: grid = 4096 blocks, 8 XCDs, 4096 % 8 == 0.
    // Physical blocks round-robin XCDs, so XCD k executes logical ids
    // [k*512, (k+1)*512) in order -> adjacent row-strips share their boundary
    // row within one XCD's L2.
    const int bid   = blockIdx.x;
    const int chunk = gridDim.x >> 3;               // 4096/8 = 512
    const int lid   = (bid & 7) * chunk + (bid >> 3);

    const int np = threadIdx.x;                      // 0..255 column-pair
    const int t  = lid & 127;                        // row-strip within image
    const int b  = lid >> 7;                         // batch

    const int n0 = np << 1;
    const int n2 = (n0 + 2 < 512) ? n0 + 2 : 511;    // clamp only at np==255
    const int m0 = t << 2;                           // first input row of strip

    const size_t base = (size_t)b * (512 * 512);

    // Load R+1 rows x 3 cols (all addresses known up front -> max load ILP).
    float4 p[R + 1][3];
#pragma unroll
    for (int r = 0; r <= R; ++r) {
        int mm = m0 + r;
        mm = (mm < 512) ? mm : 511;                  // symmetric-pad clamp (last strip only)
        const size_t row = base + (size_t)mm * 512;
        p[r][0] = x[row + n0];
        p[r][1] = x[row + n0 + 1];
        p[r][2] = x[row + n2];
    }

    // Per-row channel state: A = c0+c1 (both take the lpf/lpf path), z = c2, w = c3.
    float A[R + 1][3], z[R + 1][3], w[R + 1][3];
#pragma unroll
    for (int r = 0; r <= R; ++r) {
#pragma unroll
        for (int j = 0; j < 3; ++j) {
            A[r][j] = p[r][j].x + p[r][j].y;
            z[r][j] = p[r][j].z;
            w[r][j] = p[r][j].w;
        }
    }

    // out: [B, 1024, 1024] fp32 = rows of 256 float4; this thread owns
    // output rows 2*m0 .. 2*m0+7, float4-col np.
    size_t o = (size_t)((b << 10) + (m0 << 1)) * 256 + np;

#pragma unroll
    for (int r = 0; r < R; ++r) {
        float Lv0[3], Lv1[3], Hv0[3], Hv1[3];
#pragma unroll
        for (int j = 0; j < 3; ++j) {
            Lv0[j] = h2 * A[r][j] + h0 * A[r + 1][j];
            Lv1[j] = h3 * A[r][j] + h1 * A[r + 1][j];
            Hv0[j] = (h2 * z[r][j] + h0 * z[r + 1][j]) + (h1 * w[r][j] + h3 * w[r + 1][j]);
            Hv1[j] = (h3 * z[r][j] + h1 * z[r + 1][j]) + (-h0 * w[r][j] - h2 * w[r + 1][j]);
        }

        // horizontal: lpf ec=0 (h2,h0), ec=1 (h3,h1); hpf ec=0 (h1,h3), ec=1 (-h0,-h2)
        float4 r0, r1;
        r0.x = h2 * Lv0[0] + h0 * Lv0[1] + h1 * Hv0[0] + h3 * Hv0[1];
        r0.y = h3 * Lv0[0] + h1 * Lv0[1] - h0 * Hv0[0] - h2 * Hv0[1];
        r0.z = h2 * Lv0[1] + h0 * Lv0[2] + h1 * Hv0[1] + h3 * Hv0[2];
        r0.w = h3 * Lv0[1] + h1 * Lv0[2] - h0 * Hv0[1] - h2 * Hv0[2];
        r1.x = h2 * Lv1[0] + h0 * Lv1[1] + h1 * Hv1[0] + h3 * Hv1[1];
        r1.y = h3 * Lv1[0] + h1 * Lv1[1] - h0 * Hv1[0] - h2 * Hv1[1];
        r1.z = h2 * Lv1[1] + h0 * Lv1[2] + h1 * Hv1[1] + h3 * Hv1[2];
        r1.w = h3 * Lv1[1] + h1 * Lv1[2] - h0 * Hv1[1] - h2 * Hv1[2];

        out[o]       = r0;
        out[o + 256] = r1;
        o += 512;
    }
}

extern "C" void kernel_launch(void* const* d_in, const int* in_sizes, int n_in,
                              void* d_out, int out_size, void* d_ws, size_t ws_size,
                              hipStream_t stream) {
    const float4* x = (const float4*)d_in[0];
    float4* out = (float4*)d_out;
    // one thread per (b, 4-row strip, column-pair): 32 * 128 * 256 threads
    const int blocks = 32 * 128;   // 4096, divisible by 8 (bijective XCD swizzle)
    idwt_kernel<<<blocks, 256, 0, stream>>>(x, out);
}